// Round 9
// baseline (498.901 us; speedup 1.0000x reference)
//
#include <hip/hip_runtime.h>
#include <cstdint>

// Problem dims
#define Bdim 8192   // batch
#define Hdim 1024   // hidden units (per gate)
#define Kdim 2048   // IN + H
// ---- 8-wave 256-row tile; A staged in LDS (depth-3, 4 slots); B (weights)
// ---- streamed GLOBAL->REGISTER (L1/L2-served, bypassing LDS entirely) ----
// Rationale: rounds 2/7/8 (three different schedules) all converge at
// ~181 us with the LDS pipe ~56% busy and every MFMA dependent on it.
// B frag reads were 2/3 of LDS read traffic (x4 M-wave amplification) and
// B stage was 1/2 of write traffic. The 4 M-waves read IDENTICAL W bytes
// per phase -> L1 broadcast; a u0-column's W slice (1 MB bf16) is
// L2-resident; all of W (16 MB) is L3-resident. Moving B to the TA/L1 pipe
// unloads LDS by 2.7x and lets the two pipes overlap.
// Block: 256 rows x 64 units x 4 gates, 512 thr = 8 waves (4M x 2U);
// wave = 64 rows x 32 units x 4 gates, acc[2][4] floatx16 (128 AGPR).
// Phase p (one 32-k slab, ONE barrier, ONE counted vmcnt):
//   BLOAD(p): 8 x 16B global loads -> fB regs (per-lane row = unit)
//   STAGE_A(p+3 -> slot (p+3)%4): 2 gload_lds
//   READ4(slot p%4): 4 ds_read_b128 -> fA
//   vmcnt(2): retires {A(p+2), B(p)}, leaves {A(p+3)} (never 0)
//   [compiler counted lgkm] setprio(1); 16 MFMA; setprio(0); barrier
// Ledger: entering phase p outstanding = {A(p+2)} = 2. WAR: slot (p+3)%4
// was read at phase p-1, retired before p-1's closing barrier.
// LDS: 4 A-slots x 16 KB = 64 KB. A slab layout (proven): [row][4 chunks
// of 8, chunk c at slot c^((row>>1)&3)], source-side swizzle, linear dest.

#define NSLAB (Kdim / 32)   // 64 slabs
#define SLAB  (256 * 32)    // elems per A slab: 16 KB

#define XELEMS ((size_t)Bdim * Kdim)        // 16,777,216
#define WELEMS ((size_t)4 * Hdim * Kdim)    //  8,388,608
#define WGATE  ((size_t)Hdim * Kdim)        //  2,097,152

typedef __bf16 bf16;
typedef bf16  bf16x8   __attribute__((ext_vector_type(8)));
typedef float floatx16 __attribute__((ext_vector_type(16)));

typedef __attribute__((address_space(1))) uint32_t gu32;
typedef __attribute__((address_space(3))) uint32_t lu32;

__device__ __forceinline__ void gl_lds16(const bf16* g, bf16* l) {
    __builtin_amdgcn_global_load_lds((gu32*)(bf16*)g, (lu32*)l, 16, 0, 0);
}

__device__ __forceinline__ float sigf(float x) {
    return 1.0f / (1.0f + __expf(-x));
}
__device__ __forceinline__ float tanhfast(float x) {
    return 2.0f / (1.0f + __expf(-2.0f * x)) - 1.0f;
}

// ---------------- fp32 -> bf16 conversion pre-pass ----------------
__global__ __launch_bounds__(256) void cvt_kernel(
    const float* __restrict__ inp, const float* __restrict__ hid,
    const float* __restrict__ Wf,  const float* __restrict__ Wi,
    const float* __restrict__ Wo,  const float* __restrict__ Wc,
    bf16* __restrict__ xc, bf16* __restrict__ wc)
{
    const size_t id = (size_t)blockIdx.x * 256 + threadIdx.x;  // 8-elem chunk
    const size_t e  = id * 8;
    const float* src;
    bf16* dst;
    if (e < XELEMS) {
        const size_t b = e >> 11;          // row (K=2048)
        const size_t k = e & (Kdim - 1);
        src = (k < Hdim) ? (hid + b * Hdim + k) : (inp + b * Hdim + (k - Hdim));
        dst = xc + e;
    } else {
        const size_t w = e - XELEMS;
        const size_t g = w >> 21;          // 2^21 == H*K
        const float* Ws = (g == 0) ? Wf : (g == 1) ? Wi : (g == 2) ? Wo : Wc;
        src = Ws + (w & (WGATE - 1));
        dst = wc + w;
    }
    const float4 a  = *reinterpret_cast<const float4*>(src);
    const float4 b4 = *reinterpret_cast<const float4*>(src + 4);
    bf16x8 o;
    o[0] = (bf16)a.x;  o[1] = (bf16)a.y;  o[2] = (bf16)a.z;  o[3] = (bf16)a.w;
    o[4] = (bf16)b4.x; o[5] = (bf16)b4.y; o[6] = (bf16)b4.z; o[7] = (bf16)b4.w;
    *reinterpret_cast<bf16x8*>(dst) = o;
}

// ---------------- fused LSTM GEMM + epilogue ----------------
// 32x32x16 MFMA. A-operand: A[m = lane&31][k = (lane>>5)*8 + j] (B symmetric:
// B[n = lane&31][k = (lane>>5)*8 + j] -> per-lane 16B global read).
// C/D layout (m74/m101): col = lane&31, row = (reg&3) + 8*(reg>>2) + 4*(lane>>5).
__global__ __launch_bounds__(512, 2) void lstm_fused(
    const bf16* __restrict__ xc,   const bf16* __restrict__ wc,
    const float* __restrict__ cin,
    const float* __restrict__ bfv, const float* __restrict__ biv,
    const float* __restrict__ bov, const float* __restrict__ bcv,
    float* __restrict__ out)
{
    __shared__ __align__(16) bf16 As[4 * SLAB];   // [slot][256r][32k] 64 KB

    const int tid  = threadIdx.x;
    const int lane = tid & 63;
    const int wv   = tid >> 6;          // 0..7
    const int m31  = lane & 31;
    const int h32  = lane >> 5;

    const int m0 = blockIdx.x * 256;
    const int u0 = blockIdx.y * 64;

    // ---- A staging setup (source-side swizzle; LDS dest = base + lane*16) ----
    // per slab: 1024 16B-chunks, 512 threads x 2. li = c*512+tid; row = li>>2.
    const bf16* gA[2];
    bf16* lA[2];
    #pragma unroll
    for (int c = 0; c < 2; ++c) {
        const int li   = c * 512 + tid;
        const int row  = li >> 2;           // 0..255
        const int slot = li & 3;
        const int gch  = slot ^ ((row >> 1) & 3);
        gA[c] = xc + (size_t)(m0 + row) * Kdim + gch * 8;
        lA[c] = &As[li * 8];
    }

    // ---- fragment read offsets (A, elements within a slab) ----
    const int rbase = (wv & 3) * 64;    // 4 M-waves
    const int ubase = (wv >> 2) * 32;   // 2 U-waves
    int aoff[2][2];                     // [a: row frag][h: k-half of slab]
    #pragma unroll
    for (int a = 0; a < 2; ++a) {
        const int ra = rbase + a * 32 + m31;
        const int t  = (ra >> 1) & 3;
        #pragma unroll
        for (int h = 0; h < 2; ++h)
            aoff[a][h] = ra * 32 + (((h * 2 + h32) ^ t) * 8);
    }

    // ---- B (weights) global base pointers: per-lane row = u0+ubase+m31 ----
    const bf16* wB[4];
    #pragma unroll
    for (int g = 0; g < 4; ++g)
        wB[g] = wc + (size_t)g * WGATE + (size_t)(u0 + ubase + m31) * Kdim
                   + h32 * 8;

    floatx16 acc[2][4] = {};            // [a: row frag][g: gate]
    bf16x8 fA[2][2], fB[4][2];          // per-phase fragments

    // stage A slab p into LDS slot `slot` (2 gload_lds per thread)
#define STAGE_A(slot, p) do {                                       \
        const int kk_  = (p) * 32;                                  \
        const int off_ = (slot) * SLAB;                             \
        gl_lds16(gA[0] + kk_, lA[0] + off_);                        \
        gl_lds16(gA[1] + kk_, lA[1] + off_);                        \
    } while (0)

    // 8 x 16B global loads -> fB (B[n=m31][k=h*16 + h32*8 + j] per frag)
#define BLOAD(p) do {                                                         \
        const int kb_ = (p) * 32;                                             \
        _Pragma("unroll")                                                     \
        for (int g_ = 0; g_ < 4; ++g_)                                        \
            _Pragma("unroll")                                                 \
            for (int h_ = 0; h_ < 2; ++h_)                                    \
                fB[g_][h_] = *reinterpret_cast<const bf16x8*>(                \
                    wB[g_] + kb_ + h_ * 16);                                  \
    } while (0)

    // 4 ds_read_b128: both k-halves of one A slab
#define READ4(slot) do {                                                      \
        const bf16* Ab_ = As + (slot) * SLAB;                                 \
        fA[0][0] = *reinterpret_cast<const bf16x8*>(Ab_ + aoff[0][0]);        \
        fA[1][0] = *reinterpret_cast<const bf16x8*>(Ab_ + aoff[1][0]);        \
        fA[0][1] = *reinterpret_cast<const bf16x8*>(Ab_ + aoff[0][1]);        \
        fA[1][1] = *reinterpret_cast<const bf16x8*>(Ab_ + aoff[1][1]);        \
    } while (0)

#define MFMA16() do {                                                         \
        __builtin_amdgcn_s_setprio(1);                                        \
        _Pragma("unroll")                                                     \
        for (int h_ = 0; h_ < 2; ++h_)                                        \
            _Pragma("unroll")                                                 \
            for (int a_ = 0; a_ < 2; ++a_)                                    \
                _Pragma("unroll")                                             \
                for (int g_ = 0; g_ < 4; ++g_)                                \
                    acc[a_][g_] = __builtin_amdgcn_mfma_f32_32x32x16_bf16(    \
                        fA[a_][h_], fB[g_][h_], acc[a_][g_], 0, 0, 0);        \
        __builtin_amdgcn_s_setprio(0);                                        \
    } while (0)

#define BAR() do {                                                            \
        __builtin_amdgcn_s_barrier();                                         \
        asm volatile("" ::: "memory");                                        \
    } while (0)

    // ---- prologue: A slabs 0,1,2 -> slots 0,1,2 ----
    STAGE_A(0, 0);
    STAGE_A(1, 1);
    STAGE_A(2, 2);
    asm volatile("s_waitcnt vmcnt(4)" ::: "memory");   // A(0) landed (own)
    BAR();
    // entering phase 0: outstanding = {A(1), A(2)} = 4 (steady: {A(p+2)} = 2)

    // one phase: B(p) -> regs, stage A(p+3) (clamped), read+MFMA A slab p.
#define PHASE(slot_c, slot_s, p) do {                               \
        const int pn_ = ((p) + 3 < NSLAB) ? (p) + 3 : NSLAB - 1;    \
        BLOAD(p);                                                   \
        STAGE_A(slot_s, pn_);                                       \
        READ4(slot_c);                                              \
        asm volatile("s_waitcnt vmcnt(2)" ::: "memory");            \
        MFMA16();                                                   \
        BAR();                                                      \
    } while (0)

    #pragma unroll 1
    for (int pp = 0; pp < NSLAB; pp += 4) {
        PHASE(0, 3, pp);
        PHASE(1, 0, pp + 1);
        PHASE(2, 1, pp + 2);
        PHASE(3, 2, pp + 3);
    }
#undef PHASE
#undef BAR
#undef MFMA16
#undef READ4
#undef BLOAD
#undef STAGE_A

    // ---- fused LSTM epilogue (one unit per lane) ----
    const int m_base = m0 + rbase + 4 * h32;
    const int unit   = u0 + ubase + m31;
    const float bff = bfv[unit];
    const float bii = biv[unit];
    const float boo = bov[unit];
    const float bcc = bcv[unit];
    #pragma unroll
    for (int a = 0; a < 2; ++a) {
        #pragma unroll
        for (int rg = 0; rg < 16; ++rg) {
            const int row = m_base + a * 32 + (rg & 3) + 8 * (rg >> 2);
            const size_t off = (size_t)row * Hdim + unit;
            const float fg = sigf(acc[a][0][rg] + bff);
            const float ig = sigf(acc[a][1][rg] + bii);
            const float og = sigf(acc[a][2][rg] + boo);
            const float ch = tanhfast(acc[a][3][rg] + bcc);
            const float cn = fg * cin[off] + ig * ch;
            const float hn = og * tanhfast(cn);
            out[off] = hn;                         // h_new
            out[(size_t)Bdim * Hdim + off] = cn;   // c_new
        }
    }
}

extern "C" void kernel_launch(void* const* d_in, const int* in_sizes, int n_in,
                              void* d_out, int out_size, void* d_ws, size_t ws_size,
                              hipStream_t stream) {
    const float* inputs = (const float*)d_in[0];
    const float* hidden = (const float*)d_in[1];
    const float* cprev  = (const float*)d_in[2];
    const float* Wf     = (const float*)d_in[3];
    const float* bfp    = (const float*)d_in[4];
    const float* Wi     = (const float*)d_in[5];
    const float* bip    = (const float*)d_in[6];
    const float* Wo     = (const float*)d_in[7];
    const float* bop    = (const float*)d_in[8];
    const float* Wc     = (const float*)d_in[9];
    const float* bcp    = (const float*)d_in[10];
    float* out = (float*)d_out;

    const size_t need = (XELEMS + WELEMS) * sizeof(bf16);
    if (ws_size < need) return;
    bf16* xc = (bf16*)d_ws;
    bf16* wc = xc + XELEMS;

    const int cvt_blocks = (int)((XELEMS + WELEMS) / 8 / 256);  // 12288
    cvt_kernel<<<dim3(cvt_blocks), dim3(256), 0, stream>>>(
        inputs, hidden, Wf, Wi, Wo, Wc, xc, wc);

    dim3 grid(Bdim / 256, Hdim / 64);   // 32 x 16 = 512 blocks, 1 block/CU
    lstm_fused<<<grid, dim3(512), 0, stream>>>(
        xc, wc, cprev, bfp, bip, bop, bcp, out);
}

// Round 10
// 327.432 us; speedup vs baseline: 1.5237x; 1.5237x over previous
//
#include <hip/hip_runtime.h>
#include <cstdint>

// Problem dims
#define Bdim 8192   // batch
#define Hdim 1024   // hidden units (per gate)
#define Kdim 2048   // IN + H
// ---- 8-wave 256-row tile, depth-3 prefetch (4 slots), INTRA-PHASE
// ---- READ/MFMA OVERLAP (half-slab software pipeline, 2 barriers/phase) ----
// Round-8 base (proven 181us) reordered so every MFMA cluster runs with
// 6 ds_read_b128 in flight beneath it (the m201 pacing):
//   phase p:
//     subA: R(p,h1) issue ; [sched pin] ; MFMA8(h0)   (consumes R(p,h0))
//     subB: STAGE(p+3 -> slot (p+3)%4) ; vmcnt(8) ; BAR ;
//           R(p+1,h0) issue ; [sched pin] ; MFMA8(h1) ; BAR
// Ledger (T4, never 0): entering phase p outstanding = {G(p+1),G(p+2)} = 8;
// stage -> 12; vmcnt(8) retires G(p+1); BAR certifies it CHIP-WIDE before
// any wave reads slot (p+1)%4 (no cross-wave vmcnt race). WAR: stage target
// slot (p+3)%4 = (p-1)%4; its last reads retired before p-1's closing BAR.
// Frag live set = 12 bf16x8 (48 VGPR) -- identical to round 8, no spill.
// Tail: stages clamp to slab 63 (uniform vmcnt); phase 63's R(64,h0) is dead.
// LDS: 4 slab-slots x (A 16 KB + B 16 KB) = 128 KB, 1 block/CU.
// Slab layout (proven): [row][4 chunks of 8, chunk c at slot c^((row>>1)&3)],
// source-side swizzle, linear gl_lds dest.

#define NSLAB (Kdim / 32)   // 64 slabs
#define SLAB  (256 * 32)    // elems per slab (A and B identical): 16 KB

#define XELEMS ((size_t)Bdim * Kdim)        // 16,777,216
#define WELEMS ((size_t)4 * Hdim * Kdim)    //  8,388,608
#define WGATE  ((size_t)Hdim * Kdim)        //  2,097,152

typedef __bf16 bf16;
typedef bf16  bf16x8   __attribute__((ext_vector_type(8)));
typedef float floatx16 __attribute__((ext_vector_type(16)));

typedef __attribute__((address_space(1))) uint32_t gu32;
typedef __attribute__((address_space(3))) uint32_t lu32;

__device__ __forceinline__ void gl_lds16(const bf16* g, bf16* l) {
    __builtin_amdgcn_global_load_lds((gu32*)(bf16*)g, (lu32*)l, 16, 0, 0);
}

__device__ __forceinline__ float sigf(float x) {
    return 1.0f / (1.0f + __expf(-x));
}
__device__ __forceinline__ float tanhfast(float x) {
    return 2.0f / (1.0f + __expf(-2.0f * x)) - 1.0f;
}

// ---------------- fp32 -> bf16 conversion pre-pass ----------------
__global__ __launch_bounds__(256) void cvt_kernel(
    const float* __restrict__ inp, const float* __restrict__ hid,
    const float* __restrict__ Wf,  const float* __restrict__ Wi,
    const float* __restrict__ Wo,  const float* __restrict__ Wc,
    bf16* __restrict__ xc, bf16* __restrict__ wc)
{
    const size_t id = (size_t)blockIdx.x * 256 + threadIdx.x;  // 8-elem chunk
    const size_t e  = id * 8;
    const float* src;
    bf16* dst;
    if (e < XELEMS) {
        const size_t b = e >> 11;          // row (K=2048)
        const size_t k = e & (Kdim - 1);
        src = (k < Hdim) ? (hid + b * Hdim + k) : (inp + b * Hdim + (k - Hdim));
        dst = xc + e;
    } else {
        const size_t w = e - XELEMS;
        const size_t g = w >> 21;          // 2^21 == H*K
        const float* Ws = (g == 0) ? Wf : (g == 1) ? Wi : (g == 2) ? Wo : Wc;
        src = Ws + (w & (WGATE - 1));
        dst = wc + w;
    }
    const float4 a  = *reinterpret_cast<const float4*>(src);
    const float4 b4 = *reinterpret_cast<const float4*>(src + 4);
    bf16x8 o;
    o[0] = (bf16)a.x;  o[1] = (bf16)a.y;  o[2] = (bf16)a.z;  o[3] = (bf16)a.w;
    o[4] = (bf16)b4.x; o[5] = (bf16)b4.y; o[6] = (bf16)b4.z; o[7] = (bf16)b4.w;
    *reinterpret_cast<bf16x8*>(dst) = o;
}

// ---------------- fused LSTM GEMM + epilogue ----------------
// 32x32x16 MFMA. A-operand: A[m = lane&31][k = (lane>>5)*8 + j] (B symmetric).
// C/D layout (m74/m101): col = lane&31, row = (reg&3) + 8*(reg>>2) + 4*(lane>>5).
__global__ __launch_bounds__(512, 2) void lstm_fused(
    const bf16* __restrict__ xc,   const bf16* __restrict__ wc,
    const float* __restrict__ cin,
    const float* __restrict__ bfv, const float* __restrict__ biv,
    const float* __restrict__ bov, const float* __restrict__ bcv,
    float* __restrict__ out)
{
    __shared__ __align__(16) bf16 As[4 * SLAB];   // [slot][256r][32k] 64 KB
    __shared__ __align__(16) bf16 Bs[4 * SLAB];   // [slot][4g*64u][32k] 64 KB

    const int tid  = threadIdx.x;
    const int lane = tid & 63;
    const int wv   = tid >> 6;          // 0..7
    const int m31  = lane & 31;
    const int h32  = lane >> 5;

    const int m0 = blockIdx.x * 256;
    const int u0 = blockIdx.y * 64;

    // ---- staging setup (source-side swizzle; LDS dest = base + lane*16) ----
    // per slab: 1024 16B-chunks, 512 threads x 2. li = c*512+tid; row = li>>2.
    const bf16* gA[2];
    bf16* lA[2];
    const bf16* gB[2];
    bf16* lB[2];
    #pragma unroll
    for (int c = 0; c < 2; ++c) {
        const int li   = c * 512 + tid;
        const int row  = li >> 2;           // 0..255
        const int slot = li & 3;
        const int gch  = slot ^ ((row >> 1) & 3);
        gA[c] = xc + (size_t)(m0 + row) * Kdim + gch * 8;
        lA[c] = &As[li * 8];
        const int g  = row >> 6;            // gate
        const int ul = row & 63;            // unit within block
        gB[c] = wc + (size_t)g * WGATE + (size_t)(u0 + ul) * Kdim + gch * 8;
        lB[c] = &Bs[li * 8];
    }

    // ---- fragment read offsets (elements within a slab) ----
    const int rbase = (wv & 3) * 64;    // 4 M-waves
    const int ubase = (wv >> 2) * 32;   // 2 U-waves
    int aoff[2][2];                     // [a: row frag][h: k-half of slab]
    #pragma unroll
    for (int a = 0; a < 2; ++a) {
        const int ra = rbase + a * 32 + m31;
        const int t  = (ra >> 1) & 3;
        #pragma unroll
        for (int h = 0; h < 2; ++h)
            aoff[a][h] = ra * 32 + (((h * 2 + h32) ^ t) * 8);
    }
    int boff[4][2];                     // [g: gate][h]
    #pragma unroll
    for (int g = 0; g < 4; ++g) {
        const int rb = g * 64 + ubase + m31;
        const int t  = (rb >> 1) & 3;
        #pragma unroll
        for (int h = 0; h < 2; ++h)
            boff[g][h] = rb * 32 + (((h * 2 + h32) ^ t) * 8);
    }

    floatx16 acc[2][4] = {};            // [a: row frag][g: gate]
    bf16x8 fA[2][2], fB[4][2];          // [.][h] fragments (12 live, 48 VGPR)

    // stage slab p into LDS slot `slot` (4 gload_lds per thread)
#define STAGE_G(slot, p) do {                                       \
        const int kk_  = (p) * 32;                                  \
        const int off_ = (slot) * SLAB;                             \
        gl_lds16(gA[0] + kk_, lA[0] + off_);                        \
        gl_lds16(gA[1] + kk_, lA[1] + off_);                        \
        gl_lds16(gB[0] + kk_, lB[0] + off_);                        \
        gl_lds16(gB[1] + kk_, lB[1] + off_);                        \
    } while (0)

    // 6 ds_read_b128: one k-half h of one slab slot
#define READ6(slot, h) do {                                                   \
        const bf16* Ab_ = As + (slot) * SLAB;                                 \
        const bf16* Bb_ = Bs + (slot) * SLAB;                                 \
        fA[0][h] = *reinterpret_cast<const bf16x8*>(Ab_ + aoff[0][h]);        \
        fA[1][h] = *reinterpret_cast<const bf16x8*>(Ab_ + aoff[1][h]);        \
        fB[0][h] = *reinterpret_cast<const bf16x8*>(Bb_ + boff[0][h]);        \
        fB[1][h] = *reinterpret_cast<const bf16x8*>(Bb_ + boff[1][h]);        \
        fB[2][h] = *reinterpret_cast<const bf16x8*>(Bb_ + boff[2][h]);        \
        fB[3][h] = *reinterpret_cast<const bf16x8*>(Bb_ + boff[3][h]);        \
    } while (0)

    // 8 MFMAs consuming k-half h
#define MFMA8(h) do {                                                         \
        __builtin_amdgcn_s_setprio(1);                                        \
        _Pragma("unroll")                                                     \
        for (int a_ = 0; a_ < 2; ++a_)                                        \
            _Pragma("unroll")                                                 \
            for (int g_ = 0; g_ < 4; ++g_)                                    \
                acc[a_][g_] = __builtin_amdgcn_mfma_f32_32x32x16_bf16(        \
                    fA[a_][h], fB[g_][h], acc[a_][g_], 0, 0, 0);              \
        __builtin_amdgcn_s_setprio(0);                                        \
    } while (0)

#define BAR() do {                                                            \
        __builtin_amdgcn_s_barrier();                                         \
        asm volatile("" ::: "memory");                                        \
    } while (0)
#define SPIN() __builtin_amdgcn_sched_barrier(0)

    // ---- prologue: slabs 0,1,2 -> slots 0,1,2; pre-issue R(0,h0) ----
    STAGE_G(0, 0);
    STAGE_G(1, 1);
    STAGE_G(2, 2);
    asm volatile("s_waitcnt vmcnt(8)" ::: "memory");   // G(0) landed (own)
    BAR();                                             // ... chip-wide
    READ6(0, 0);                                       // R(0,h0) in flight
    // invariant entering phase p: outstanding vm = {G(p+1), G(p+2)} = 8,
    // and R(p,h0) has been issued.

    // one phase (slot_c = p%4, slot_n = (p+1)%4, slot_s = (p+3)%4)
#define PHASE(sc, sn, ss, p) do {                                   \
        /* subA: reads of h1 fly under MFMA of h0 */                \
        READ6(sc, 1);                                               \
        SPIN();                                                     \
        MFMA8(0);                                                   \
        /* subB */                                                  \
        {                                                           \
            const int pn_ = ((p) + 3 < NSLAB) ? (p) + 3 : NSLAB - 1;\
            STAGE_G(ss, pn_);                                       \
        }                                                           \
        asm volatile("s_waitcnt vmcnt(8)" ::: "memory");            \
        BAR();   /* G(p+1) certified chip-wide */                   \
        READ6(sn, 0);                                               \
        SPIN();                                                     \
        MFMA8(1);                                                   \
        BAR();   /* WAR fence for next phase's stage */             \
    } while (0)

    #pragma unroll 1
    for (int pp = 0; pp < NSLAB; pp += 4) {
        PHASE(0, 1, 3, pp);
        PHASE(1, 2, 0, pp + 1);
        PHASE(2, 3, 1, pp + 2);
        PHASE(3, 0, 2, pp + 3);
    }
#undef PHASE
#undef SPIN
#undef BAR
#undef MFMA8
#undef READ6
#undef STAGE_G

    // ---- fused LSTM epilogue (one unit per lane) ----
    const int m_base = m0 + rbase + 4 * h32;
    const int unit   = u0 + ubase + m31;
    const float bff = bfv[unit];
    const float bii = biv[unit];
    const float boo = bov[unit];
    const float bcc = bcv[unit];
    #pragma unroll
    for (int a = 0; a < 2; ++a) {
        #pragma unroll
        for (int rg = 0; rg < 16; ++rg) {
            const int row = m_base + a * 32 + (rg & 3) + 8 * (rg >> 2);
            const size_t off = (size_t)row * Hdim + unit;
            const float fg = sigf(acc[a][0][rg] + bff);
            const float ig = sigf(acc[a][1][rg] + bii);
            const float og = sigf(acc[a][2][rg] + boo);
            const float ch = tanhfast(acc[a][3][rg] + bcc);
            const float cn = fg * cin[off] + ig * ch;
            const float hn = og * tanhfast(cn);
            out[off] = hn;                         // h_new
            out[(size_t)Bdim * Hdim + off] = cn;   // c_new
        }
    }
}

extern "C" void kernel_launch(void* const* d_in, const int* in_sizes, int n_in,
                              void* d_out, int out_size, void* d_ws, size_t ws_size,
                              hipStream_t stream) {
    const float* inputs = (const float*)d_in[0];
    const float* hidden = (const float*)d_in[1];
    const float* cprev  = (const float*)d_in[2];
    const float* Wf     = (const float*)d_in[3];
    const float* bfp    = (const float*)d_in[4];
    const float* Wi     = (const float*)d_in[5];
    const float* bip    = (const float*)d_in[6];
    const float* Wo     = (const float*)d_in[7];
    const float* bop    = (const float*)d_in[8];
    const float* Wc     = (const float*)d_in[9];
    const float* bcp    = (const float*)d_in[10];
    float* out = (float*)d_out;

    const size_t need = (XELEMS + WELEMS) * sizeof(bf16);
    if (ws_size < need) return;
    bf16* xc = (bf16*)d_ws;
    bf16* wc = xc + XELEMS;

    const int cvt_blocks = (int)((XELEMS + WELEMS) / 8 / 256);  // 12288
    cvt_kernel<<<dim3(cvt_blocks), dim3(256), 0, stream>>>(
        inputs, hidden, Wf, Wi, Wo, Wc, xc, wc);

    dim3 grid(Bdim / 256, Hdim / 64);   // 32 x 16 = 512 blocks, 1 block/CU
    lstm_fused<<<grid, dim3(512), 0, stream>>>(
        xc, wc, cprev, bfp, bip, bop, bcp, out);
}